// Round 4
// baseline (888.875 us; speedup 1.0000x reference)
//
#include <hip/hip_runtime.h>

typedef unsigned short u16;
typedef unsigned int u32;
typedef __attribute__((ext_vector_type(8))) short bf16x8;
typedef __attribute__((ext_vector_type(4))) float f32x4;
typedef __attribute__((ext_vector_type(8))) unsigned short u16x8;

#define MFMA16 __builtin_amdgcn_mfma_f32_16x16x32_bf16

__device__ __forceinline__ u16 f2bf(float f) {
  unsigned u = __float_as_uint(f);
  u += 0x7fffu + ((u >> 16) & 1u);
  return (u16)(u >> 16);
}

__device__ __forceinline__ void async16(void* lds, const void* g) {
  __builtin_amdgcn_global_load_lds(
      (const __attribute__((address_space(1))) unsigned int*)g,
      (__attribute__((address_space(3))) unsigned int*)lds, 16, 0, 0);
}

// ---------------- f32 -> bf16 conversion (vectorized, memory-bound) --------
__global__ void convert_bf16(const float* __restrict__ in, u16* __restrict__ out, int n4) {
  int i = blockIdx.x * blockDim.x + threadIdx.x;
  int st = gridDim.x * blockDim.x;
  for (; i < n4; i += st) {
    float4 f = ((const float4*)in)[i];
    ushort4 o;
    o.x = f2bf(f.x); o.y = f2bf(f.y); o.z = f2bf(f.z); o.w = f2bf(f.w);
    ((ushort4*)out)[i] = o;
  }
}

// ---------------- GEMM core: C[128x128] tile, A[M,K] row-major bf16, -------
// ---------------- B[N,K] row-major bf16 (B^T gemm), BK=32, 4 waves ---------
__global__ __launch_bounds__(256) void gemm_qkv(
    const u16* __restrict__ A, const u16* __restrict__ B,
    u16* __restrict__ Qb, u16* __restrict__ Kb, u16* __restrict__ Vb) {
  __shared__ __align__(16) u16 lA[128 * 32];
  __shared__ __align__(16) u16 lB[128 * 32];
  const int tid = threadIdx.x;
  const int lane = tid & 63, wid = tid >> 6;
  const int wrow = wid >> 1, wcol = wid & 1;
  const int fr = lane & 15, fq = lane >> 4;
  const int tm = blockIdx.y * 128, tn = blockIdx.x * 128;
  const int K = 2048;

  f32x4 acc[4][4] = {};

  const int r0 = tid >> 2, cg = tid & 3;
  const size_t a_base = (size_t)(tm + r0) * K + cg * 8;
  const size_t b_base = (size_t)(tn + r0) * K + cg * 8;
  char* lAc = (char*)lA;
  char* lBc = (char*)lB;
  const int lo0 = (wid * 64) * 16;
  const int lo1 = (256 + wid * 64) * 16;

  for (int kt = 0; kt < K; kt += 32) {
    async16(lAc + lo0, A + a_base + kt);
    async16(lAc + lo1, A + a_base + (size_t)64 * K + kt);
    async16(lBc + lo0, B + b_base + kt);
    async16(lBc + lo1, B + b_base + (size_t)64 * K + kt);
    __syncthreads();
    bf16x8 af[4], bfr[4];
#pragma unroll
    for (int i = 0; i < 4; ++i)
      af[i] = *(const bf16x8*)&lA[(wrow * 64 + i * 16 + fr) * 32 + fq * 8];
#pragma unroll
    for (int j = 0; j < 4; ++j)
      bfr[j] = *(const bf16x8*)&lB[(wcol * 64 + j * 16 + fr) * 32 + fq * 8];
#pragma unroll
    for (int i = 0; i < 4; ++i)
#pragma unroll
      for (int j = 0; j < 4; ++j)
        acc[i][j] = MFMA16(af[i], bfr[j], acc[i][j], 0, 0, 0);
    __syncthreads();
  }

#pragma unroll
  for (int j = 0; j < 4; ++j) {
    int n = tn + wcol * 64 + j * 16 + fr;
    int which = n >> 11;
    int h = (n >> 7) & 15;
    int d = n & 127;
    u16* dst = which == 0 ? Qb : (which == 1 ? Kb : Vb);
#pragma unroll
    for (int i = 0; i < 4; ++i)
#pragma unroll
      for (int r = 0; r < 4; ++r) {
        int m = tm + wrow * 64 + i * 16 + fq * 4 + r;
        int b = m >> 11, t = m & 2047;
        dst[((size_t)((b * 16 + h) * 2048 + t) << 7) + d] = f2bf(acc[i][j][r]);
      }
  }
}

// out-projection epilogue: f32 row-major [8192,2048]
__global__ __launch_bounds__(256) void gemm_out(
    const u16* __restrict__ A, const u16* __restrict__ B, float* __restrict__ C) {
  __shared__ __align__(16) u16 lA[128 * 32];
  __shared__ __align__(16) u16 lB[128 * 32];
  const int tid = threadIdx.x;
  const int lane = tid & 63, wid = tid >> 6;
  const int wrow = wid >> 1, wcol = wid & 1;
  const int fr = lane & 15, fq = lane >> 4;
  const int tm = blockIdx.y * 128, tn = blockIdx.x * 128;
  const int K = 2048;

  f32x4 acc[4][4] = {};
  const int r0 = tid >> 2, cg = tid & 3;
  const size_t a_base = (size_t)(tm + r0) * K + cg * 8;
  const size_t b_base = (size_t)(tn + r0) * K + cg * 8;
  char* lAc = (char*)lA;
  char* lBc = (char*)lB;
  const int lo0 = (wid * 64) * 16;
  const int lo1 = (256 + wid * 64) * 16;

  for (int kt = 0; kt < K; kt += 32) {
    async16(lAc + lo0, A + a_base + kt);
    async16(lAc + lo1, A + a_base + (size_t)64 * K + kt);
    async16(lBc + lo0, B + b_base + kt);
    async16(lBc + lo1, B + b_base + (size_t)64 * K + kt);
    __syncthreads();
    bf16x8 af[4], bfr[4];
#pragma unroll
    for (int i = 0; i < 4; ++i)
      af[i] = *(const bf16x8*)&lA[(wrow * 64 + i * 16 + fr) * 32 + fq * 8];
#pragma unroll
    for (int j = 0; j < 4; ++j)
      bfr[j] = *(const bf16x8*)&lB[(wcol * 64 + j * 16 + fr) * 32 + fq * 8];
#pragma unroll
    for (int i = 0; i < 4; ++i)
#pragma unroll
      for (int j = 0; j < 4; ++j)
        acc[i][j] = MFMA16(af[i], bfr[j], acc[i][j], 0, 0, 0);
    __syncthreads();
  }

#pragma unroll
  for (int j = 0; j < 4; ++j) {
    int n = tn + wcol * 64 + j * 16 + fr;
#pragma unroll
    for (int i = 0; i < 4; ++i)
#pragma unroll
      for (int r = 0; r < 4; ++r) {
        int m = tm + wrow * 64 + i * 16 + fq * 4 + r;
        C[(size_t)m * 2048 + n] = acc[i][j][r];
      }
  }
}

// ---------------- V -> V^T (per head): Vt[pair][d][t] ----------------------
__global__ __launch_bounds__(256) void transpose_v(const u16* __restrict__ V,
                                                   u16* __restrict__ Vt) {
  __shared__ u16 lds[64 * 72];  // stride 72 u16 = 144B (16B-aligned rows)
  const int tid = threadIdx.x;
  const int pair = blockIdx.z;
  const int t0 = blockIdx.x * 64, d0 = blockIdx.y * 64;
  const u16* Vp = V + (size_t)pair * 262144;
  u16* Vtp = Vt + (size_t)pair * 262144;
#pragma unroll
  for (int it = 0; it < 2; ++it) {
    int c = it * 256 + tid;
    int t = c >> 3, ch = c & 7;
    u16x8 tv = *(const u16x8*)&Vp[(size_t)(t0 + t) * 128 + d0 + ch * 8];
#pragma unroll
    for (int jj = 0; jj < 8; ++jj) lds[(ch * 8 + jj) * 72 + t] = tv[jj];
  }
  __syncthreads();
#pragma unroll
  for (int it = 0; it < 2; ++it) {
    int c = it * 256 + tid;
    int d = c >> 3, ct = c & 7;
    u16x8 tv = *(const u16x8*)&lds[d * 72 + ct * 8];
    *(u16x8*)&Vtp[(size_t)(d0 + d) * 2048 + t0 + ct * 8] = tv;
  }
}

// ---------------- flash attention v4: round-3 math, async16 staging --------
// ---------------- (pre-swizzled global source, linear LDS dest) ------------
// grid (pair=64, by=8), 256 thr. Block handles q-blocks {by, 15-by}.
// LDS: K [64][128] swz (16K) + Vt [128][64] swz (16K) + P [128][64] swz (16K)
// = 48K -> 3 blocks/CU; __launch_bounds__(256,3) caps VGPR at 170.
__global__ __launch_bounds__(256, 3) void attn4(
    const u16* __restrict__ Q, const u16* __restrict__ K,
    const u16* __restrict__ Vt, u16* __restrict__ Y) {
  __shared__ __align__(16) char smem[49152];
  char* lK = smem;
  char* lV = smem + 16384;
  char* lP = smem + 32768;
  const int tid = threadIdx.x;
  const int lane = tid & 63, w = tid >> 6;
  const int fr = lane & 15, fq = lane >> 4;
  const int pair = blockIdx.x, by = blockIdx.y;
  const size_t hoff = (size_t)pair * 262144;
  const u16* Qh = Q + hoff;
  const u16* Kh = K + hoff;
  const u16* Vth = Vt + hoff;
  const int b = pair >> 4, h = pair & 15;
  const float c1 = 0.08838834764831845f * 1.4426950408889634f;  // D^-0.5 * log2(e)

  for (int phase = 0; phase < 2; ++phase) {
    const int qb = phase ? 15 - by : by;
    const int q0 = qb * 128;
    const int nt = 2 * qb + 2;
    const int qw = q0 + w * 32;

    bf16x8 qf[2][4];
#pragma unroll
    for (int i = 0; i < 2; ++i)
#pragma unroll
      for (int ks = 0; ks < 4; ++ks)
        qf[i][ks] = *(const bf16x8*)&Qh[(size_t)(qw + i * 16 + fr) * 128 + ks * 32 + fq * 8];

    f32x4 o[2][8] = {};
    float m2[2][4], ls[2][4];
#pragma unroll
    for (int i = 0; i < 2; ++i)
#pragma unroll
      for (int r = 0; r < 4; ++r) { m2[i][r] = -1e30f; ls[i][r] = 0.f; }

    for (int t = 0; t < nt; ++t) {
      const int kv0 = t * 64;
      // stage tile t: linear LDS dest (uniform base + lane*16), swizzled global src.
      // LDS slot s of row rr ends up holding data chunk s^(rr&7) -- identical
      // contents to round-3's verified swizzled ds_write, so reads are unchanged.
#pragma unroll
      for (int it = 0; it < 4; ++it) {
        int idx = it * 256 + tid;
        int s = idx >> 4, c = idx & 15;
        async16(lK + (it * 256 + w * 64) * 16,
                Kh + (size_t)(kv0 + s) * 128 + ((c ^ (s & 7)) * 8));
        int d = idx >> 3, c2 = idx & 7;
        async16(lV + (it * 256 + w * 64) * 16,
                Vth + (size_t)d * 2048 + kv0 + ((c2 ^ (d & 7)) * 8));
      }
      __syncthreads();  // vmcnt drained per-wave before barrier -> lK/lV ready

      if (kv0 <= qw + 31) {  // wave-uniform skip of fully-masked tiles
        // QK^T: sc[i][j], col = kv s = j*16+fr -- round-3 verbatim
        f32x4 sc[2][4] = {};
#pragma unroll
        for (int j = 0; j < 4; ++j) {
          int s = j * 16 + fr;
#pragma unroll
          for (int ks = 0; ks < 4; ++ks) {
            bf16x8 kf = *(const bf16x8*)(lK + s * 256 + (((ks * 32 + fq * 8) * 2) ^ ((s & 7) << 4)));
            sc[0][j] = MFMA16(qf[0][ks], kf, sc[0][j], 0, 0, 0);
            sc[1][j] = MFMA16(qf[1][ks], kf, sc[1][j], 0, 0, 0);
          }
        }
        // causal mask
        if (kv0 + 64 > qw) {
#pragma unroll
          for (int i = 0; i < 2; ++i) {
            int rowb = qw + i * 16 + fq * 4;
#pragma unroll
            for (int j = 0; j < 4; ++j) {
              int col = kv0 + j * 16 + fr;
#pragma unroll
              for (int r = 0; r < 4; ++r)
                if (col > rowb + r) sc[i][j][r] = -3e38f;
            }
          }
        }
        // online softmax (base-2), P -> LDS bf16 (swizzled) -- round-3 verbatim
#pragma unroll
        for (int i = 0; i < 2; ++i) {
#pragma unroll
          for (int r = 0; r < 4; ++r) {
            float v = fmaxf(fmaxf(sc[i][0][r], sc[i][1][r]), fmaxf(sc[i][2][r], sc[i][3][r]));
            v = fmaxf(v, __shfl_xor(v, 1));
            v = fmaxf(v, __shfl_xor(v, 2));
            v = fmaxf(v, __shfl_xor(v, 4));
            v = fmaxf(v, __shfl_xor(v, 8));
            v *= c1;
            float mn = fmaxf(m2[i][r], v);
            float corr = __builtin_amdgcn_exp2f(m2[i][r] - mn);
            m2[i][r] = mn;
            ls[i][r] *= corr;
#pragma unroll
            for (int n = 0; n < 8; ++n) o[i][n][r] *= corr;
            float rs = 0.f;
            int prow = w * 32 + i * 16 + fq * 4 + r;
#pragma unroll
            for (int j = 0; j < 4; ++j) {
              float p = __builtin_amdgcn_exp2f(sc[i][j][r] * c1 - mn);
              rs += p;
              *(u16*)(lP + prow * 128 + (((j * 16 + fr) * 2) ^ ((prow & 7) << 4))) = f2bf(p);
            }
            rs += __shfl_xor(rs, 1);
            rs += __shfl_xor(rs, 2);
            rs += __shfl_xor(rs, 4);
            rs += __shfl_xor(rs, 8);
            ls[i][r] += rs;
          }
        }
        // PV: o[i][n] += P(32x64) * V(64x128) -- round-3 verbatim
        bf16x8 pf[2][2];
#pragma unroll
        for (int i = 0; i < 2; ++i) {
          int prow = w * 32 + i * 16 + fr;
#pragma unroll
          for (int k2 = 0; k2 < 2; ++k2)
            pf[i][k2] = *(const bf16x8*)(lP + prow * 128 + ((k2 * 64 + fq * 16) ^ ((prow & 7) << 4)));
        }
#pragma unroll
        for (int n = 0; n < 8; ++n) {
          int d = n * 16 + fr;
#pragma unroll
          for (int k2 = 0; k2 < 2; ++k2) {
            bf16x8 vf = *(const bf16x8*)(lV + d * 128 + ((k2 * 64 + fq * 16) ^ ((d & 7) << 4)));
            o[0][n] = MFMA16(pf[0][k2], vf, o[0][n], 0, 0, 0);
            o[1][n] = MFMA16(pf[1][k2], vf, o[1][n], 0, 0, 0);
          }
        }
      }
      __syncthreads();  // all waves done reading lK/lV before next tile's stage
    }

    // epilogue: normalize, write y in [B,T,H*D] bf16 -- round-3 verbatim
#pragma unroll
    for (int i = 0; i < 2; ++i) {
      float inv[4];
#pragma unroll
      for (int r = 0; r < 4; ++r) inv[r] = 1.f / ls[i][r];
#pragma unroll
      for (int n = 0; n < 8; ++n)
#pragma unroll
        for (int r = 0; r < 4; ++r) {
          int tt = qw + i * 16 + fq * 4 + r;
          Y[((size_t)(b * 2048 + tt) * 2048) + h * 128 + n * 16 + fr] = f2bf(o[i][n][r] * inv[r]);
        }
    }
  }
}

// ---------------------------------------------------------------------------
extern "C" void kernel_launch(void* const* d_in, const int* in_sizes, int n_in,
                              void* d_out, int out_size, void* d_ws, size_t ws_size,
                              hipStream_t stream) {
  const float* x = (const float*)d_in[0];
  const float* Win = (const float*)d_in[1];
  const float* Wout = (const float*)d_in[2];
  float* out = (float*)d_out;
  char* ws = (char*)d_ws;

  u16* x_bf   = (u16*)(ws);                  // 33554432 B (reused as Vt after gemm_qkv)
  u16* win_bf = (u16*)(ws + 33554432);       // 25165824 B
  u16* wout_bf= (u16*)(ws + 58720256);       //  8388608 B
  u16* Qb     = (u16*)(ws + 67108864);       // 33554432 B
  u16* Kb     = (u16*)(ws + 100663296);      // 33554432 B
  u16* Vb     = (u16*)(ws + 134217728);      // 33554432 B
  u16* y_bf   = (u16*)(ws + 167772160);      // 33554432 B  (total 192 MiB)
  u16* Vtb    = x_bf;                        // x_bf dead after gemm_qkv

  convert_bf16<<<2048, 256, 0, stream>>>(x, x_bf, 16777216 / 4);
  convert_bf16<<<2048, 256, 0, stream>>>(Win, win_bf, 12582912 / 4);
  convert_bf16<<<1024, 256, 0, stream>>>(Wout, wout_bf, 4194304 / 4);

  gemm_qkv<<<dim3(48, 64), 256, 0, stream>>>(x_bf, win_bf, Qb, Kb, Vb);
  transpose_v<<<dim3(32, 2, 64), 256, 0, stream>>>(Vb, Vtb);
  attn4<<<dim3(64, 8), 256, 0, stream>>>(Qb, Kb, Vtb, y_bf);
  gemm_out<<<dim3(16, 64), 256, 0, stream>>>(y_bf, wout_bf, out);
}

// Round 5
// 658.690 us; speedup vs baseline: 1.3495x; 1.3495x over previous
//
#include <hip/hip_runtime.h>

typedef unsigned short u16;
typedef unsigned int u32;
typedef __attribute__((ext_vector_type(8))) short bf16x8;
typedef __attribute__((ext_vector_type(4))) float f32x4;
typedef __attribute__((ext_vector_type(8))) unsigned short u16x8;
typedef __attribute__((ext_vector_type(4))) u32 u32x4;

#define MFMA16 __builtin_amdgcn_mfma_f32_16x16x32_bf16

__device__ __forceinline__ u16 f2bf(float f) {
  unsigned u = __float_as_uint(f);
  u += 0x7fffu + ((u >> 16) & 1u);
  return (u16)(u >> 16);
}

__device__ __forceinline__ void async16(void* lds, const void* g) {
  __builtin_amdgcn_global_load_lds(
      (const __attribute__((address_space(1))) unsigned int*)g,
      (__attribute__((address_space(3))) unsigned int*)lds, 16, 0, 0);
}

// ---------------- f32 -> bf16 conversion (vectorized, memory-bound) --------
__global__ void convert_bf16(const float* __restrict__ in, u16* __restrict__ out, int n4) {
  int i = blockIdx.x * blockDim.x + threadIdx.x;
  int st = gridDim.x * blockDim.x;
  for (; i < n4; i += st) {
    float4 f = ((const float4*)in)[i];
    ushort4 o;
    o.x = f2bf(f.x); o.y = f2bf(f.y); o.z = f2bf(f.z); o.w = f2bf(f.w);
    ((ushort4*)out)[i] = o;
  }
}

// ---------------- GEMM core: C[128x128] tile, A[M,K] row-major bf16, -------
// ---------------- B[N,K] row-major bf16 (B^T gemm), BK=32, 4 waves ---------
__global__ __launch_bounds__(256) void gemm_qkv(
    const u16* __restrict__ A, const u16* __restrict__ B,
    u16* __restrict__ Qb, u16* __restrict__ Kb, u16* __restrict__ Vb) {
  __shared__ __align__(16) u16 lA[128 * 32];
  __shared__ __align__(16) u16 lB[128 * 32];
  const int tid = threadIdx.x;
  const int lane = tid & 63, wid = tid >> 6;
  const int wrow = wid >> 1, wcol = wid & 1;
  const int fr = lane & 15, fq = lane >> 4;
  const int tm = blockIdx.y * 128, tn = blockIdx.x * 128;
  const int K = 2048;

  f32x4 acc[4][4] = {};

  const int r0 = tid >> 2, cg = tid & 3;
  const size_t a_base = (size_t)(tm + r0) * K + cg * 8;
  const size_t b_base = (size_t)(tn + r0) * K + cg * 8;
  char* lAc = (char*)lA;
  char* lBc = (char*)lB;
  const int lo0 = (wid * 64) * 16;
  const int lo1 = (256 + wid * 64) * 16;

  for (int kt = 0; kt < K; kt += 32) {
    async16(lAc + lo0, A + a_base + kt);
    async16(lAc + lo1, A + a_base + (size_t)64 * K + kt);
    async16(lBc + lo0, B + b_base + kt);
    async16(lBc + lo1, B + b_base + (size_t)64 * K + kt);
    __syncthreads();
    bf16x8 af[4], bfr[4];
#pragma unroll
    for (int i = 0; i < 4; ++i)
      af[i] = *(const bf16x8*)&lA[(wrow * 64 + i * 16 + fr) * 32 + fq * 8];
#pragma unroll
    for (int j = 0; j < 4; ++j)
      bfr[j] = *(const bf16x8*)&lB[(wcol * 64 + j * 16 + fr) * 32 + fq * 8];
#pragma unroll
    for (int i = 0; i < 4; ++i)
#pragma unroll
      for (int j = 0; j < 4; ++j)
        acc[i][j] = MFMA16(af[i], bfr[j], acc[i][j], 0, 0, 0);
    __syncthreads();
  }

#pragma unroll
  for (int j = 0; j < 4; ++j) {
    int n = tn + wcol * 64 + j * 16 + fr;
    int which = n >> 11;
    int h = (n >> 7) & 15;
    int d = n & 127;
    u16* dst = which == 0 ? Qb : (which == 1 ? Kb : Vb);
#pragma unroll
    for (int i = 0; i < 4; ++i)
#pragma unroll
      for (int r = 0; r < 4; ++r) {
        int m = tm + wrow * 64 + i * 16 + fq * 4 + r;
        int b = m >> 11, t = m & 2047;
        dst[((size_t)((b * 16 + h) * 2048 + t) << 7) + d] = f2bf(acc[i][j][r]);
      }
  }
}

// out-projection epilogue: f32 row-major [8192,2048]
__global__ __launch_bounds__(256) void gemm_out(
    const u16* __restrict__ A, const u16* __restrict__ B, float* __restrict__ C) {
  __shared__ __align__(16) u16 lA[128 * 32];
  __shared__ __align__(16) u16 lB[128 * 32];
  const int tid = threadIdx.x;
  const int lane = tid & 63, wid = tid >> 6;
  const int wrow = wid >> 1, wcol = wid & 1;
  const int fr = lane & 15, fq = lane >> 4;
  const int tm = blockIdx.y * 128, tn = blockIdx.x * 128;
  const int K = 2048;

  f32x4 acc[4][4] = {};
  const int r0 = tid >> 2, cg = tid & 3;
  const size_t a_base = (size_t)(tm + r0) * K + cg * 8;
  const size_t b_base = (size_t)(tn + r0) * K + cg * 8;
  char* lAc = (char*)lA;
  char* lBc = (char*)lB;
  const int lo0 = (wid * 64) * 16;
  const int lo1 = (256 + wid * 64) * 16;

  for (int kt = 0; kt < K; kt += 32) {
    async16(lAc + lo0, A + a_base + kt);
    async16(lAc + lo1, A + a_base + (size_t)64 * K + kt);
    async16(lBc + lo0, B + b_base + kt);
    async16(lBc + lo1, B + b_base + (size_t)64 * K + kt);
    __syncthreads();
    bf16x8 af[4], bfr[4];
#pragma unroll
    for (int i = 0; i < 4; ++i)
      af[i] = *(const bf16x8*)&lA[(wrow * 64 + i * 16 + fr) * 32 + fq * 8];
#pragma unroll
    for (int j = 0; j < 4; ++j)
      bfr[j] = *(const bf16x8*)&lB[(wcol * 64 + j * 16 + fr) * 32 + fq * 8];
#pragma unroll
    for (int i = 0; i < 4; ++i)
#pragma unroll
      for (int j = 0; j < 4; ++j)
        acc[i][j] = MFMA16(af[i], bfr[j], acc[i][j], 0, 0, 0);
    __syncthreads();
  }

#pragma unroll
  for (int j = 0; j < 4; ++j) {
    int n = tn + wcol * 64 + j * 16 + fr;
#pragma unroll
    for (int i = 0; i < 4; ++i)
#pragma unroll
      for (int r = 0; r < 4; ++r) {
        int m = tm + wrow * 64 + i * 16 + fq * 4 + r;
        C[(size_t)m * 2048 + n] = acc[i][j][r];
      }
  }
}

// ---------------- V -> V^T (per head): Vt[pair][d][t] ----------------------
__global__ __launch_bounds__(256) void transpose_v(const u16* __restrict__ V,
                                                   u16* __restrict__ Vt) {
  __shared__ u16 lds[64 * 72];  // stride 72 u16 = 144B (16B-aligned rows)
  const int tid = threadIdx.x;
  const int pair = blockIdx.z;
  const int t0 = blockIdx.x * 64, d0 = blockIdx.y * 64;
  const u16* Vp = V + (size_t)pair * 262144;
  u16* Vtp = Vt + (size_t)pair * 262144;
#pragma unroll
  for (int it = 0; it < 2; ++it) {
    int c = it * 256 + tid;
    int t = c >> 3, ch = c & 7;
    u16x8 tv = *(const u16x8*)&Vp[(size_t)(t0 + t) * 128 + d0 + ch * 8];
#pragma unroll
    for (int jj = 0; jj < 8; ++jj) lds[(ch * 8 + jj) * 72 + t] = tv[jj];
  }
  __syncthreads();
#pragma unroll
  for (int it = 0; it < 2; ++it) {
    int c = it * 256 + tid;
    int d = c >> 3, ct = c & 7;
    u16x8 tv = *(const u16x8*)&lds[d * 72 + ct * 8];
    *(u16x8*)&Vtp[(size_t)(d0 + d) * 2048 + t0 + ct * 8] = tv;
  }
}

// ---------------- flash attention v5: round-3 reg-staged math + ------------
// ---------------- double-buffered K/V, ONE barrier per tile ----------------
// grid (pair=64, by=8), 256 thr. Block handles q-blocks {by, 15-by}.
// LDS: 2 x (K 16K + Vt 16K) + P 16K = 80K -> 2 blocks/CU (LDS-capped).
// Safety: ds_write(t) targets buf[t&1]; its last readers ran compute(t-2),
// finished before every wave arrived at barrier(t-1). One barrier/tile.
__global__ __launch_bounds__(256) void attn5(
    const u16* __restrict__ Q, const u16* __restrict__ K,
    const u16* __restrict__ Vt, u16* __restrict__ Y) {
  __shared__ __align__(16) char smem[81920];
  char* lP = smem + 65536;
  const int tid = threadIdx.x;
  const int lane = tid & 63, w = tid >> 6;
  const int fr = lane & 15, fq = lane >> 4;
  const int pair = blockIdx.x, by = blockIdx.y;
  const size_t hoff = (size_t)pair * 262144;
  const u16* Qh = Q + hoff;
  const u16* Kh = K + hoff;
  const u16* Vth = Vt + hoff;
  const int b = pair >> 4, h = pair & 15;
  const float c1 = 0.08838834764831845f * 1.4426950408889634f;  // D^-0.5 * log2(e)

  // per-thread staging coordinates: K chunk (s,c), V chunk (d,c2)
  int ksr[4], kcc[4], vdr[4], vcc[4];
#pragma unroll
  for (int it = 0; it < 4; ++it) {
    int idx = it * 256 + tid;
    ksr[it] = idx >> 4; kcc[it] = idx & 15;   // K: row 0..63, chunk 0..15
    vdr[it] = idx >> 3; vcc[it] = idx & 7;    // V: row 0..127, chunk 0..7
  }

  for (int phase = 0; phase < 2; ++phase) {
    const int qb = phase ? 15 - by : by;
    const int q0 = qb * 128;
    const int nt = 2 * qb + 2;
    const int qw = q0 + w * 32;

    bf16x8 qf[2][4];
#pragma unroll
    for (int i = 0; i < 2; ++i)
#pragma unroll
      for (int ks = 0; ks < 4; ++ks)
        qf[i][ks] = *(const bf16x8*)&Qh[(size_t)(qw + i * 16 + fr) * 128 + ks * 32 + fq * 8];

    f32x4 o[2][8] = {};
    float m2[2][4], ls[2][4];
#pragma unroll
    for (int i = 0; i < 2; ++i)
#pragma unroll
      for (int r = 0; r < 4; ++r) { m2[i][r] = -1e30f; ls[i][r] = 0.f; }

    // preload tile 0 into registers
    u32x4 kst[4], vst[4];
#pragma unroll
    for (int it = 0; it < 4; ++it) {
      kst[it] = *(const u32x4*)&Kh[(size_t)ksr[it] * 128 + kcc[it] * 8];
      vst[it] = *(const u32x4*)&Vth[(size_t)vdr[it] * 2048 + vcc[it] * 8];
    }

    for (int t = 0; t < nt; ++t) {
      const int kv0 = t * 64;
      char* lK = smem + (t & 1) * 32768;
      char* lV = lK + 16384;
      // ds_write staged tile t (swizzled) into buf[t&1] -- free per barrier arg above
#pragma unroll
      for (int it = 0; it < 4; ++it) {
        *(u32x4*)(lK + ksr[it] * 256 + ((kcc[it] ^ (ksr[it] & 7)) << 4)) = kst[it];
        *(u32x4*)(lV + vdr[it] * 128 + ((vcc[it] ^ (vdr[it] & 7)) << 4)) = vst[it];
      }
      // issue next-tile global loads (consumed by next iteration's ds_write)
      if (t + 1 < nt) {
        const int nk = kv0 + 64;
#pragma unroll
        for (int it = 0; it < 4; ++it) {
          kst[it] = *(const u32x4*)&Kh[(size_t)(nk + ksr[it]) * 128 + kcc[it] * 8];
          vst[it] = *(const u32x4*)&Vth[(size_t)vdr[it] * 2048 + nk + vcc[it] * 8];
        }
      }
      __syncthreads();  // buf[t&1] visible to all; ONLY barrier this tile

      if (kv0 <= qw + 31) {  // wave-uniform skip of fully-masked tiles
        // QK^T: sc[i][j], col = kv s = j*16+fr -- round-3 verbatim
        f32x4 sc[2][4] = {};
#pragma unroll
        for (int j = 0; j < 4; ++j) {
          int s = j * 16 + fr;
#pragma unroll
          for (int ks = 0; ks < 4; ++ks) {
            bf16x8 kf = *(const bf16x8*)(lK + s * 256 + (((ks * 32 + fq * 8) * 2) ^ ((s & 7) << 4)));
            sc[0][j] = MFMA16(qf[0][ks], kf, sc[0][j], 0, 0, 0);
            sc[1][j] = MFMA16(qf[1][ks], kf, sc[1][j], 0, 0, 0);
          }
        }
        // causal mask
        if (kv0 + 64 > qw) {
#pragma unroll
          for (int i = 0; i < 2; ++i) {
            int rowb = qw + i * 16 + fq * 4;
#pragma unroll
            for (int j = 0; j < 4; ++j) {
              int col = kv0 + j * 16 + fr;
#pragma unroll
              for (int r = 0; r < 4; ++r)
                if (col > rowb + r) sc[i][j][r] = -3e38f;
            }
          }
        }
        // online softmax (base-2), P -> LDS bf16 (swizzled) -- round-3 verbatim
#pragma unroll
        for (int i = 0; i < 2; ++i) {
#pragma unroll
          for (int r = 0; r < 4; ++r) {
            float v = fmaxf(fmaxf(sc[i][0][r], sc[i][1][r]), fmaxf(sc[i][2][r], sc[i][3][r]));
            v = fmaxf(v, __shfl_xor(v, 1));
            v = fmaxf(v, __shfl_xor(v, 2));
            v = fmaxf(v, __shfl_xor(v, 4));
            v = fmaxf(v, __shfl_xor(v, 8));
            v *= c1;
            float mn = fmaxf(m2[i][r], v);
            float corr = __builtin_amdgcn_exp2f(m2[i][r] - mn);
            m2[i][r] = mn;
            ls[i][r] *= corr;
#pragma unroll
            for (int n = 0; n < 8; ++n) o[i][n][r] *= corr;
            float rs = 0.f;
            int prow = w * 32 + i * 16 + fq * 4 + r;
#pragma unroll
            for (int j = 0; j < 4; ++j) {
              float p = __builtin_amdgcn_exp2f(sc[i][j][r] * c1 - mn);
              rs += p;
              *(u16*)(lP + prow * 128 + (((j * 16 + fr) * 2) ^ ((prow & 7) << 4))) = f2bf(p);
            }
            rs += __shfl_xor(rs, 1);
            rs += __shfl_xor(rs, 2);
            rs += __shfl_xor(rs, 4);
            rs += __shfl_xor(rs, 8);
            ls[i][r] += rs;
          }
        }
        // PV: o[i][n] += P(32x64) * V(64x128) -- round-3 verbatim (P per-wave private)
        bf16x8 pf[2][2];
#pragma unroll
        for (int i = 0; i < 2; ++i) {
          int prow = w * 32 + i * 16 + fr;
#pragma unroll
          for (int k2 = 0; k2 < 2; ++k2)
            pf[i][k2] = *(const bf16x8*)(lP + prow * 128 + ((k2 * 64 + fq * 16) ^ ((prow & 7) << 4)));
        }
#pragma unroll
        for (int n = 0; n < 8; ++n) {
          int d = n * 16 + fr;
#pragma unroll
          for (int k2 = 0; k2 < 2; ++k2) {
            bf16x8 vf = *(const bf16x8*)(lV + d * 128 + ((k2 * 64 + fq * 16) ^ ((d & 7) << 4)));
            o[0][n] = MFMA16(pf[0][k2], vf, o[0][n], 0, 0, 0);
            o[1][n] = MFMA16(pf[1][k2], vf, o[1][n], 0, 0, 0);
          }
        }
      }
      // no trailing barrier: next tile writes the OTHER buffer
    }
    __syncthreads();  // protect buffers before next phase's ds_write

    // epilogue: normalize, write y in [B,T,H*D] bf16 -- round-3 verbatim
#pragma unroll
    for (int i = 0; i < 2; ++i) {
      float inv[4];
#pragma unroll
      for (int r = 0; r < 4; ++r) inv[r] = 1.f / ls[i][r];
#pragma unroll
      for (int n = 0; n < 8; ++n)
#pragma unroll
        for (int r = 0; r < 4; ++r) {
          int tt = qw + i * 16 + fq * 4 + r;
          Y[((size_t)(b * 2048 + tt) * 2048) + h * 128 + n * 16 + fr] = f2bf(o[i][n][r] * inv[r]);
        }
    }
  }
}

// ---------------------------------------------------------------------------
extern "C" void kernel_launch(void* const* d_in, const int* in_sizes, int n_in,
                              void* d_out, int out_size, void* d_ws, size_t ws_size,
                              hipStream_t stream) {
  const float* x = (const float*)d_in[0];
  const float* Win = (const float*)d_in[1];
  const float* Wout = (const float*)d_in[2];
  float* out = (float*)d_out;
  char* ws = (char*)d_ws;

  u16* x_bf   = (u16*)(ws);                  // 33554432 B (reused as Vt after gemm_qkv)
  u16* win_bf = (u16*)(ws + 33554432);       // 25165824 B
  u16* wout_bf= (u16*)(ws + 58720256);       //  8388608 B
  u16* Qb     = (u16*)(ws + 67108864);       // 33554432 B
  u16* Kb     = (u16*)(ws + 100663296);      // 33554432 B
  u16* Vb     = (u16*)(ws + 134217728);      // 33554432 B
  u16* y_bf   = (u16*)(ws + 167772160);      // 33554432 B  (total 192 MiB)
  u16* Vtb    = x_bf;                        // x_bf dead after gemm_qkv

  convert_bf16<<<2048, 256, 0, stream>>>(x, x_bf, 16777216 / 4);
  convert_bf16<<<2048, 256, 0, stream>>>(Win, win_bf, 12582912 / 4);
  convert_bf16<<<1024, 256, 0, stream>>>(Wout, wout_bf, 4194304 / 4);

  gemm_qkv<<<dim3(48, 64), 256, 0, stream>>>(x_bf, win_bf, Qb, Kb, Vb);
  transpose_v<<<dim3(32, 2, 64), 256, 0, stream>>>(Vb, Vtb);
  attn5<<<dim3(64, 8), 256, 0, stream>>>(Qb, Kb, Vtb, y_bf);
  gemm_out<<<dim3(16, 64), 256, 0, stream>>>(y_bf, wout_bf, out);
}